// Round 5
// baseline (476.474 us; speedup 1.0000x reference)
//
#include <hip/hip_runtime.h>
#include <hip/hip_bf16.h>
#include <math.h>

// Problem constants (fixed by setup_inputs)
#define Bb   4
#define Hh   16
#define Tt   4096
#define Dd   64
#define Pp   128
#define MAXN 32
#define BHc  64   // B*H

// ---------------- precompute: cos/sin table for global positions ----------------
__global__ void k_postab(float* __restrict__ postab) {
    int idx = blockIdx.x * blockDim.x + threadIdx.x;
    if (idx >= Tt * 16) return;
    int pos = idx >> 4, fi = idx & 15;
    float inv = (float)pow(10000.0, -(double)fi / 16.0);
    float ang = (float)pos * inv;
    postab[idx * 2 + 0] = cosf(ang);
    postab[idx * 2 + 1] = sinf(ang);
}

// ---------------- precompute: region starts + region cos/sin table ----------------
__global__ void k_prep(const int* __restrict__ regions, float* __restrict__ regtab,
                       int* __restrict__ starts) {
    int i = threadIdx.x;
    if (i < Bb * MAXN) {
        int b = i >> 5, n = (i & 31) + 1;
        const int* r = regions + b * Tt;
        int lo = 0, hi = Tt;
        while (lo < hi) { int mid = (lo + hi) >> 1; if (r[mid] < n) lo = mid + 1; else hi = mid; }
        starts[i] = (lo < Tt && r[lo] == n) ? lo : 0;
    }
    int j = i - Bb * MAXN;
    if (j >= 0 && j < 33 * 16) {
        int pos = j >> 4, fi = j & 15;
        float inv = (float)pow(10000.0, -(double)fi / 16.0);
        float ang = (float)pos * inv;
        regtab[j * 2 + 0] = cosf(ang);
        regtab[j * 2 + 1] = sinf(ang);
    }
}

// ---------------- DIAGNOSTIC main kernel: all-f32 VALU flash attention ----------------
// grid = BH * NS, block = 256. Threads 0..127 each own one pool row p; threads
// 128..255 help stage only. No MFMA, no bf16, no LDS swizzle, no V transpose.
__global__ __launch_bounds__(256) void k_attn(
    const float* __restrict__ q_in, const float* __restrict__ k_in,
    const float* __restrict__ v_in, const int* __restrict__ regions,
    const float* __restrict__ bias_same, const float* __restrict__ bias_diff,
    const float* __restrict__ postab, const float* __restrict__ regtab,
    const int* __restrict__ starts, float* __restrict__ pO,
    float* __restrict__ pML, int NS)
{
    const int bid   = blockIdx.x;
    const int chunk = bid % NS;
    const int bh    = bid / NS;
    const int b     = bh >> 4;
    const int h     = bh & 15;
    const int C     = Tt / NS;
    const int NTILE = C >> 6;
    const int c0    = chunk * C;

    const int tid = threadIdx.x;

    __shared__ __align__(16) float Kf[64][64];
    __shared__ __align__(16) float Vf[64][64];
    __shared__ __align__(16) float rtab[33 * 16 * 2];
    __shared__ int regs_s[64];
    __shared__ int starts_s[MAXN];

    for (int j = tid; j < 33 * 16 * 2; j += 256) rtab[j] = regtab[j];
    if (tid < MAXN) starts_s[tid] = starts[b * MAXN + tid];
    const float bs = bias_same[h];
    const float bd = bias_diff[h];
    __syncthreads();

    // ---- per-thread: rope q row p into registers (f32) ----
    const int p = tid & 127;
    const int myridx = (p >> 2) + 1;
    float q[64], o[64];
    {
        const float* Qp = q_in + (size_t)bh * Pp * Dd + (size_t)p * Dd;
        const int gpos = starts_s[p >> 2];
#pragma unroll
        for (int i = 0; i < 32; ++i) {
            float2 x = ((const float2*)Qp)[i];
            float2 cs;
            if (i < 16) cs = *(const float2*)(postab + (size_t)(gpos * 16 + i) * 2);
            else        cs = *(const float2*)(&rtab[(myridx * 16 + (i - 16)) * 2]);
            q[2 * i]     = x.x * cs.x - x.y * cs.y;
            q[2 * i + 1] = x.x * cs.y + x.y * cs.x;
        }
#pragma unroll
        for (int d = 0; d < 64; ++d) o[d] = 0.f;
    }
    float m = -INFINITY, lsum = 0.f;

    const float* Kbh = k_in + (size_t)bh * Tt * Dd;
    const float* Vbh = v_in + (size_t)bh * Tt * Dd;

    for (int tt = 0; tt < NTILE; ++tt) {
        const int t0 = c0 + tt * 64;
        __syncthreads();   // previous tile's reads done
        if (tid < 64) regs_s[tid] = regions[b * Tt + t0 + tid];

        // ---- stage K tile with rope (f32), all 256 threads ----
#pragma unroll
        for (int it = 0; it < 4; ++it) {
            int f   = tid + 256 * it;
            int row = f >> 4;
            int dq  = (f & 15) << 2;
            float4 x = ((const float4*)(Kbh + (size_t)t0 * Dd))[f];
            int fi = (dq & 31) >> 1;
            float4 cs;
            if (dq < 32) {
                cs = *(const float4*)(postab + (size_t)((t0 + row) * 16 + fi) * 2);
            } else {
                int rg = regions[b * Tt + t0 + row];
                cs = *(const float4*)(&rtab[(rg * 16 + fi) * 2]);
            }
            Kf[row][dq + 0] = x.x * cs.x - x.y * cs.y;
            Kf[row][dq + 1] = x.x * cs.y + x.y * cs.x;
            Kf[row][dq + 2] = x.z * cs.z - x.w * cs.w;
            Kf[row][dq + 3] = x.z * cs.w + x.w * cs.z;
        }

        // ---- stage V tile (straight f32 copy) ----
#pragma unroll
        for (int it = 0; it < 4; ++it) {
            int f   = tid + 256 * it;
            int row = f >> 4;
            int dq  = (f & 15) << 2;
            float4 x = ((const float4*)(Vbh + (size_t)t0 * Dd))[f];
            *(float4*)(&Vf[row][dq]) = x;
        }
        __syncthreads();

        // ---- compute: threads 0..127, serial over the 64 keys ----
        if (tid < 128) {
            for (int j = 0; j < 64; ++j) {
                float s0 = 0.f, s1 = 0.f, s2 = 0.f, s3 = 0.f;
#pragma unroll
                for (int d = 0; d < 64; d += 4) {
                    s0 += q[d + 0] * Kf[j][d + 0];
                    s1 += q[d + 1] * Kf[j][d + 1];
                    s2 += q[d + 2] * Kf[j][d + 2];
                    s3 += q[d + 3] * Kf[j][d + 3];
                }
                float s = (s0 + s1) + (s2 + s3);
                s = s * 0.125f + ((myridx == regs_s[j]) ? bs : bd);
                if (s <= m) {
                    float e = __expf(s - m);
                    lsum += e;
#pragma unroll
                    for (int d = 0; d < 64; ++d) o[d] += e * Vf[j][d];
                } else {
                    float c = __expf(m - s);
                    m = s;
                    lsum = lsum * c + 1.f;
#pragma unroll
                    for (int d = 0; d < 64; ++d) o[d] = o[d] * c + Vf[j][d];
                }
            }
        }
    }

    // ---- write partials ----
    if (tid < 128) {
        size_t obase = (size_t)(bh * NS + chunk) * Pp * Dd + (size_t)p * Dd;
#pragma unroll
        for (int d = 0; d < 64; ++d) pO[obase + d] = o[d];
        size_t mlb = (size_t)(bh * NS + chunk) * Pp;
        *(float2*)(pML + (mlb + p) * 2) = make_float2(m, lsum);
    }
}

// ---------------- combine partials across T-chunks ----------------
__global__ void k_combine(const float* __restrict__ pO, const float* __restrict__ pML,
                          float* __restrict__ out, int NS) {
    int bh = blockIdx.x >> 2;
    int pq = blockIdx.x & 3;
    int d  = threadIdx.x & 63;
    int ps = threadIdx.x >> 6;
    for (int pp = 0; pp < 8; ++pp) {
        int p = pq * 32 + pp * 4 + ps;
        float M = -INFINITY;
        float mv[8], lv[8];
        for (int c = 0; c < NS; ++c) {
            float2 ml = *(const float2*)(pML + ((size_t)(bh * NS + c) * Pp + p) * 2);
            mv[c] = ml.x; lv[c] = ml.y;
            M = fmaxf(M, ml.x);
        }
        float L = 0.f, o = 0.f;
        for (int c = 0; c < NS; ++c) {
            float wgt = __expf(mv[c] - M);
            L += wgt * lv[c];
            o += wgt * pO[((size_t)(bh * NS + c) * Pp + p) * Dd + d];
        }
        out[((size_t)bh * Pp + p) * Dd + d] = o / L;
    }
}

// ---------------- launcher ----------------
extern "C" void kernel_launch(void* const* d_in, const int* in_sizes, int n_in,
                              void* d_out, int out_size, void* d_ws, size_t ws_size,
                              hipStream_t stream) {
    const float* q         = (const float*)d_in[0];
    const float* k         = (const float*)d_in[1];
    const float* v         = (const float*)d_in[2];
    const int*   regions   = (const int*)d_in[3];
    const float* bias_same = (const float*)d_in[7];
    const float* bias_diff = (const float*)d_in[8];

    float* ws     = (float*)d_ws;
    float* postab = ws;                              // 4096*16*2 floats
    float* regtab = postab + Tt * 16 * 2;            // 33*16*2 floats
    int*   starts = (int*)(regtab + 33 * 16 * 2);    // 128 ints
    float* pbase  = (float*)(starts + 128);
    size_t fixed_b = (size_t)((char*)pbase - (char*)ws);

    int NS = 8;
    while (NS > 1 && fixed_b + (size_t)BHc * NS * Pp * (Dd + 2) * 4 > ws_size) NS >>= 1;
    float* pO  = pbase;
    float* pML = pO + (size_t)BHc * NS * Pp * Dd;

    k_postab<<<dim3(Tt * 16 / 256), dim3(256), 0, stream>>>(postab);
    k_prep<<<dim3(1), dim3(704), 0, stream>>>(regions, regtab, starts);
    k_attn<<<dim3(BHc * NS), dim3(256), 0, stream>>>(q, k, v, regions, bias_same, bias_diff,
                                                     postab, regtab, starts, pO, pML, NS);
    k_combine<<<dim3(BHc * 4), dim3(256), 0, stream>>>(pO, pML, (float*)d_out, NS);
}